// Round 6
// baseline (6338.915 us; speedup 1.0000x reference)
//
#include <hip/hip_runtime.h>

#define TT 512
#define BB 256
#define II 128
#define HH 256
#define LDH 264  // shorts/LDS row: 512B data + 16B pad (keeps 16B row alignment)

typedef __attribute__((ext_vector_type(8))) short short8;
typedef __attribute__((ext_vector_type(4))) float floatx4;
typedef __attribute__((ext_vector_type(4))) float fvec4;
typedef unsigned long long u64;

// ws layout (shorts): bf16 weights, h1g[2][B][H], h2g[2][B][H], then flags.
#define OFF_WIH0 0
#define OFF_WHH0 (OFF_WIH0 + 3 * HH * II)
#define OFF_WIH1 (OFF_WHH0 + 3 * HH * HH)
#define OFF_WHH1 (OFF_WIH1 + 3 * HH * HH)
#define W_TOTAL (OFF_WHH1 + 3 * HH * HH)
#define H1G_OFF W_TOTAL
#define H2G_OFF (H1G_OFF + 2 * BB * HH)
#define WS_SHORTS (H2G_OFF + 2 * BB * HH)
#define FLAGS_OFF_BYTES (WS_SHORTS * 2)
#define FLAG_STRIDE 32  // uints per bt-group; 16 flags live in one 64B line

__device__ __forceinline__ short f2bf(float f) {
  unsigned u = __builtin_bit_cast(unsigned, f);
  u = u + 0x7fffu + ((u >> 16) & 1u);
  return (short)(u >> 16);
}
__device__ __forceinline__ float fast_sigmoid(float x) {
  return __fdividef(1.0f, 1.0f + __expf(-x));
}
__device__ __forceinline__ float fast_tanh(float x) {
  return 1.0f - __fdividef(2.0f, 1.0f + __expf(2.0f * x));
}
__device__ __forceinline__ short8 cvt8(const float* __restrict__ p) {
  fvec4 lo = *(const fvec4*)p;
  fvec4 hi = *(const fvec4*)(p + 4);
  short8 r;
  r[0] = f2bf(lo[0]); r[1] = f2bf(lo[1]); r[2] = f2bf(lo[2]); r[3] = f2bf(lo[3]);
  r[4] = f2bf(hi[0]); r[5] = f2bf(hi[1]); r[6] = f2bf(hi[2]); r[7] = f2bf(hi[3]);
  return r;
}
__device__ __forceinline__ u64 ld_sc1(const u64* p) {
  return __hip_atomic_load(p, __ATOMIC_RELAXED, __HIP_MEMORY_SCOPE_AGENT);
}
__device__ __forceinline__ unsigned ld_flag(const unsigned* p) {
  return __hip_atomic_load(p, __ATOMIC_RELAXED, __HIP_MEMORY_SCOPE_AGENT);
}
__device__ __forceinline__ void st_flag(unsigned* p, unsigned v) {
  __hip_atomic_store(p, v, __ATOMIC_RELAXED, __HIP_MEMORY_SCOPE_AGENT);
}

__global__ __launch_bounds__(256) void cvt_weights(
    const float* __restrict__ w0, const float* __restrict__ w1,
    const float* __restrict__ w2, const float* __restrict__ w3,
    short* __restrict__ out) {
  int i = blockIdx.x * 256 + threadIdx.x;
  if (i >= W_TOTAL) return;
  float v;
  if (i < OFF_WHH0)      v = w0[i - OFF_WIH0];
  else if (i < OFF_WIH1) v = w1[i - OFF_WHH0];
  else if (i < OFF_WHH1) v = w2[i - OFF_WIH1];
  else                   v = w3[i - OFF_WHH1];
  out[i] = f2bf(v);
}

__global__ __launch_bounds__(256) void init_state(unsigned* __restrict__ hz,
                                                  unsigned* __restrict__ flags) {
  int i = blockIdx.x * 256 + threadIdx.x;
  if (i < 2 * BB * HH) hz[i] = 0u;  // h1g+h2g = 4*B*H shorts = 2*B*H uints
  if (i < 16 * FLAG_STRIDE) flags[i] = 0u;
}

// 64 blocks = (q 0..3) x (ht 0..15), 384 thr = 6 waves.
// Each block time-slices FOUR independent bt-groups {q, q+4, q+8, q+12}.
// Per slot, the per-group protocol is byte-identical to the verified
// agent-scope round-3 protocol (own 16-flag line, own h regions, own
// parities). Group X's publish->next-poll gap spans the other 3 groups'
// slots, so the ~7000-cycle exchange chain is hidden behind useful work
// instead of being exposed every step. Weights depend only on ht, so all
// 4 groups share the same weight VGPRs.
__global__ __launch_bounds__(384) void gru_sync(
    const float* __restrict__ x, const short* __restrict__ wb,
    const float* __restrict__ bih0, const float* __restrict__ bhh0,
    const float* __restrict__ bih1, const float* __restrict__ bhh1,
    const float* __restrict__ Wfc, const float* __restrict__ bfc,
    short* __restrict__ h1g, short* __restrict__ h2g,
    unsigned* __restrict__ flags, float* __restrict__ out) {
  const int tid = threadIdx.x;
  const int lane = tid & 63;
  const int w = tid >> 6;
  const int quad = lane >> 4;
  const int col = lane & 15;
  const int q = blockIdx.x & 3;    // group base: bt(g) = q + 4*g
  const int ht = blockIdx.x >> 2;  // 0..15
  const int layer = w / 3, gate = w % 3;
  const int j = ht * 16 + col;

  __shared__ __align__(16) short ldsA[4][2][16][LDH];  // per group: h1[p-1], h2[p-2]
  __shared__ __align__(16) float gt[4][2][6][16][20];  // per group: IH acc, HH acc

  // ---- weights -> VGPRs (wave-uniform role; shared by all 4 groups) ----
  const short* wih = wb + (layer ? OFF_WIH1 : OFF_WIH0);
  const short* whh = wb + (layer ? OFF_WHH1 : OFF_WHH0);
  short8 wfI[8], wfH[8];
  if (layer == 0) {
#pragma unroll
    for (int f = 0; f < 4; ++f)
      wfI[f] = *(const short8*)(wih + (gate * HH + j) * II + f * 32 + quad * 8);
#pragma unroll
    for (int f = 4; f < 8; ++f) wfI[f] = short8{0, 0, 0, 0, 0, 0, 0, 0};
  } else {
#pragma unroll
    for (int f = 0; f < 8; ++f)
      wfI[f] = *(const short8*)(wih + (gate * HH + j) * HH + f * 32 + quad * 8);
  }
#pragma unroll
  for (int f = 0; f < 8; ++f)
    wfH[f] = *(const short8*)(whh + (gate * HH + j) * HH + f * 32 + quad * 8);

  const float* bihL = layer ? bih1 : bih0;
  const float* bhhL = layer ? bhh1 : bhh0;
  float bI, bH;
  if (gate == 2) { bI = bihL[2 * HH + j]; bH = bhhL[2 * HH + j]; }
  else { bI = bihL[gate * HH + j] + bhhL[gate * HH + j]; bH = 0.f; }

  // ---- elementwise roles: 2 adjacent cols per thread, stable over phases ----
  const int r1 = tid >> 3, c1 = (tid & 7) * 2;                  // tid < 128
  const int r2 = (tid - 256) >> 3, c2 = ((tid - 256) & 7) * 2;  // tid >= 256

  // per-group recurrence state (named scalars: no runtime reg indexing)
  float h1aA = 0.f, h1bA = 0.f, h2aA = 0.f, h2bA = 0.f;
  float h1aB = 0.f, h1bB = 0.f, h2aB = 0.f, h2bB = 0.f;
  float h1aC = 0.f, h1bC = 0.f, h2aC = 0.f, h2bC = 0.f;
  float h1aD = 0.f, h1bD = 0.f, h2aD = 0.f, h2bD = 0.f;

  // one slot = one group's round-3 step, verbatim
  auto slot = [&](int g, int p, short8 (&ax)[4], float& h1a, float& h1b,
                  float& h2a, float& h2b) {
    unsigned* fl = flags + (q + 4 * g) * FLAG_STRIDE;
    const size_t tbase = (size_t)((q + 4 * g) * 16) * HH;

    if (p > 0) {
      if (w == 3) {  // wave 3 polls: 16-lane parallel, one ballot per round
        const unsigned tgt = (unsigned)p;
        int guard = 0;
        for (;;) {
          unsigned v = tgt;
          if (lane < 16) v = ld_flag(fl + lane);
          if (__all(v >= tgt) || ++guard > (1 << 20)) break;
        }
      }
      __syncthreads();
    }

    // ---- stage peer tiles: loads -> regs (one wait), then LDS writes ----
    {
      const u64* s1 = (const u64*)(h1g + ((p + 1) & 1) * BB * HH + tbase);
      const u64* s2 = (const u64*)(h2g + (p & 1) * BB * HH + tbase);
      u64 t1[4], t2[4];
      if (tid < 256) {
#pragma unroll
        for (int qq = 0; qq < 4; ++qq) t1[qq] = ld_sc1(s1 + tid * 4 + qq);
      }
      if (tid >= 128) {
        const int ti = tid - 128;
#pragma unroll
        for (int qq = 0; qq < 4; ++qq) t2[qq] = ld_sc1(s2 + ti * 4 + qq);
      }
      u64* d1 = (u64*)&ldsA[g][0][0][0];
      u64* d2 = (u64*)&ldsA[g][1][0][0];
      if (tid < 256) {
#pragma unroll
        for (int qq = 0; qq < 4; ++qq) {
          int i = tid * 4 + qq, row = i >> 6, c = i & 63;
          d1[row * (LDH / 4) + c] = t1[qq];
        }
      }
      if (tid >= 128) {
        const int ti = tid - 128;
#pragma unroll
        for (int qq = 0; qq < 4; ++qq) {
          int i = ti * 4 + qq, row = i >> 6, c = i & 63;
          d2[row * (LDH / 4) + c] = t2[qq];
        }
      }
    }
    __syncthreads();

    // ---- MFMA (weights in regs, A frags from LDS) ----
    floatx4 aI = floatx4{bI, bI, bI, bI};
    floatx4 aH = floatx4{bH, bH, bH, bH};
    const short* a1 = &ldsA[g][0][col][0];
    const short* a2 = &ldsA[g][1][col][0];
    if (layer == 0) {
      if (p < TT) {
#pragma unroll
        for (int f = 0; f < 4; ++f)
          aI = __builtin_amdgcn_mfma_f32_16x16x32_bf16(ax[f], wfI[f], aI, 0, 0, 0);
      }
#pragma unroll
      for (int f = 0; f < 8; ++f) {
        short8 a = *(const short8*)(a1 + f * 32 + quad * 8);
        aH = __builtin_amdgcn_mfma_f32_16x16x32_bf16(a, wfH[f], aH, 0, 0, 0);
      }
    } else {
#pragma unroll
      for (int f = 0; f < 8; ++f) {
        short8 a = *(const short8*)(a1 + f * 32 + quad * 8);
        aI = __builtin_amdgcn_mfma_f32_16x16x32_bf16(a, wfI[f], aI, 0, 0, 0);
      }
#pragma unroll
      for (int f = 0; f < 8; ++f) {
        short8 a = *(const short8*)(a2 + f * 32 + quad * 8);
        aH = __builtin_amdgcn_mfma_f32_16x16x32_bf16(a, wfH[f], aH, 0, 0, 0);
      }
    }
#pragma unroll
    for (int i = 0; i < 4; ++i) {
      gt[g][0][w][quad * 4 + i][col] = aI[i];
      gt[g][1][w][quad * 4 + i][col] = aH[i];
    }
    __syncthreads();

    // ---- elementwise + publish (agent-scope stores; compiler drains) ----
    if (tid < 128 && p < TT) {
      float rA = fast_sigmoid(gt[g][0][0][r1][c1] + gt[g][1][0][r1][c1]);
      float zA = fast_sigmoid(gt[g][0][1][r1][c1] + gt[g][1][1][r1][c1]);
      float nA = fast_tanh(gt[g][0][2][r1][c1] + rA * gt[g][1][2][r1][c1]);
      h1a = nA + zA * (h1a - nA);
      float rB = fast_sigmoid(gt[g][0][0][r1][c1 + 1] + gt[g][1][0][r1][c1 + 1]);
      float zB = fast_sigmoid(gt[g][0][1][r1][c1 + 1] + gt[g][1][1][r1][c1 + 1]);
      float nB = fast_tanh(gt[g][0][2][r1][c1 + 1] + rB * gt[g][1][2][r1][c1 + 1]);
      h1b = nB + zB * (h1b - nB);
      unsigned val = ((unsigned)(unsigned short)f2bf(h1b) << 16) |
                     (unsigned)(unsigned short)f2bf(h1a);
      unsigned* dst = (unsigned*)(h1g + (p & 1) * BB * HH +
                                  ((q + 4 * g) * 16 + r1) * HH + ht * 16 + c1);
      __hip_atomic_store(dst, val, __ATOMIC_RELAXED, __HIP_MEMORY_SCOPE_AGENT);
    }
    if (tid >= 256 && p > 0) {
      float rA = fast_sigmoid(gt[g][0][3][r2][c2] + gt[g][1][3][r2][c2]);
      float zA = fast_sigmoid(gt[g][0][4][r2][c2] + gt[g][1][4][r2][c2]);
      float nA = fast_tanh(gt[g][0][5][r2][c2] + rA * gt[g][1][5][r2][c2]);
      h2a = nA + zA * (h2a - nA);
      float rB = fast_sigmoid(gt[g][0][3][r2][c2 + 1] + gt[g][1][3][r2][c2 + 1]);
      float zB = fast_sigmoid(gt[g][0][4][r2][c2 + 1] + gt[g][1][4][r2][c2 + 1]);
      float nB = fast_tanh(gt[g][0][5][r2][c2 + 1] + rB * gt[g][1][5][r2][c2 + 1]);
      h2b = nB + zB * (h2b - nB);
      unsigned val = ((unsigned)(unsigned short)f2bf(h2b) << 16) |
                     (unsigned)(unsigned short)f2bf(h2a);
      unsigned* dst = (unsigned*)(h2g + ((p + 1) & 1) * BB * HH +
                                  ((q + 4 * g) * 16 + r2) * HH + ht * 16 + c2);
      __hip_atomic_store(dst, val, __ATOMIC_RELAXED, __HIP_MEMORY_SCOPE_AGENT);
    }
    __syncthreads();  // compiler-inserted vmcnt(0) drains the atomic stores
    if (tid == 0) st_flag(fl + ht, (unsigned)(p + 1));  // plain store, no RMW
  };

  for (int p = 0; p <= TT; ++p) {
    // x prefetch for all 4 groups (normal cached loads, issued up front)
    short8 axA[4], axB[4], axC[4], axD[4];
    if (w < 3 && p < TT) {
      const float* xr = x + ((size_t)p * BB + q * 16 + col) * II + quad * 8;
#pragma unroll
      for (int f = 0; f < 4; ++f) {
        axA[f] = cvt8(xr + f * 32);
        axB[f] = cvt8(xr + 64 * II + f * 32);
        axC[f] = cvt8(xr + 128 * II + f * 32);
        axD[f] = cvt8(xr + 192 * II + f * 32);
      }
    }
    slot(0, p, axA, h1aA, h1bA, h2aA, h2bA);
    slot(1, p, axB, h1aB, h1bB, h2aB, h2bB);
    slot(2, p, axC, h1aC, h1bC, h2aC, h2bC);
    slot(3, p, axD, h1aD, h1bD, h2aD, h2bD);
  }

  // ---- FC epilogue: out = h2[511] @ Wfc^T + bfc, all 4 groups ----
  if (w == 3) {  // 64 lanes cover 4 groups x 16 flags
    const unsigned tgt = (unsigned)(TT + 1);
    int guard = 0;
    for (;;) {
      unsigned v = ld_flag(flags + (q + 4 * (lane >> 4)) * FLAG_STRIDE + (lane & 15));
      if (__all(v >= tgt) || ++guard > (1 << 20)) break;
    }
  }
  __syncthreads();
  if (tid < 256) {
#pragma unroll
    for (int g = 0; g < 4; ++g) {
      const size_t tb = (size_t)((q + 4 * g) * 16) * HH;
      const u64* s1 = (const u64*)(h2g + 1 * BB * HH + tb);  // parity (TT+1)&1=1
      u64 t1[4];
#pragma unroll
      for (int qq = 0; qq < 4; ++qq) t1[qq] = ld_sc1(s1 + tid * 4 + qq);
      u64* d1 = (u64*)&ldsA[g][0][0][0];
#pragma unroll
      for (int qq = 0; qq < 4; ++qq) {
        int i = tid * 4 + qq, row = i >> 6, c = i & 63;
        d1[row * (LDH / 4) + c] = t1[qq];
      }
    }
  }
  __syncthreads();
  if (w < 4) {
    const int g = w;  // wave g -> group g
    float bbv = bfc[j];
    floatx4 acc = floatx4{bbv, bbv, bbv, bbv};
#pragma unroll
    for (int f = 0; f < 8; ++f) {
      short8 a = *(const short8*)(&ldsA[g][0][col][0] + f * 32 + quad * 8);
      short8 bfrag = cvt8(Wfc + j * HH + f * 32 + quad * 8);
      acc = __builtin_amdgcn_mfma_f32_16x16x32_bf16(a, bfrag, acc, 0, 0, 0);
    }
#pragma unroll
    for (int i = 0; i < 4; ++i)
      out[(size_t)((q + 4 * g) * 16 + quad * 4 + i) * HH + j] = acc[i];
  }
}

extern "C" void kernel_launch(void* const* d_in, const int* in_sizes, int n_in,
                              void* d_out, int out_size, void* d_ws,
                              size_t ws_size, hipStream_t stream) {
  const float* x = (const float*)d_in[0];
  const float* Wih0 = (const float*)d_in[1];
  const float* Whh0 = (const float*)d_in[2];
  const float* bih0 = (const float*)d_in[3];
  const float* bhh0 = (const float*)d_in[4];
  const float* Wih1 = (const float*)d_in[5];
  const float* Whh1 = (const float*)d_in[6];
  const float* bih1 = (const float*)d_in[7];
  const float* bhh1 = (const float*)d_in[8];
  const float* Wfc = (const float*)d_in[9];
  const float* bfc = (const float*)d_in[10];

  short* wb = (short*)d_ws;
  short* h1g = wb + H1G_OFF;
  short* h2g = wb + H2G_OFF;
  unsigned* flags = (unsigned*)((char*)d_ws + FLAGS_OFF_BYTES);
  unsigned* hz = (unsigned*)(wb + H1G_OFF);

  cvt_weights<<<(W_TOTAL + 255) / 256, 256, 0, stream>>>(Wih0, Whh0, Wih1, Whh1, wb);
  init_state<<<(2 * BB * HH + 255) / 256, 256, 0, stream>>>(hz, flags);
  gru_sync<<<64, 384, 0, stream>>>(x, wb, bih0, bhh0, bih1, bhh1, Wfc, bfc,
                                   h1g, h2g, flags, (float*)d_out);
}

// Round 7
// 2921.162 us; speedup vs baseline: 2.1700x; 2.1700x over previous
//
#include <hip/hip_runtime.h>

#define TT 512
#define BB 256
#define II 128
#define HH 256
#define LDH 264  // shorts/LDS row: 512B data + 16B pad (keeps 16B row alignment)

typedef __attribute__((ext_vector_type(8))) short short8;
typedef __attribute__((ext_vector_type(4))) float floatx4;
typedef __attribute__((ext_vector_type(4))) float fvec4;
typedef unsigned long long u64;

// ws layout: bf16 weights (shorts), then h1t/h2t tagged-word arrays (u64).
// Tagged word = (tag << 32) | (2 x bf16). Tag = write_step + 1.
#define OFF_WIH0 0
#define OFF_WHH0 (OFF_WIH0 + 3 * HH * II)
#define OFF_WIH1 (OFF_WHH0 + 3 * HH * HH)
#define OFF_WHH1 (OFF_WIH1 + 3 * HH * HH)
#define W_TOTAL (OFF_WHH1 + 3 * HH * HH)
#define HPAR (BB * (HH / 2))            // u64 words per parity = 32768
#define HT_WORDS (2 * HPAR)             // 65536 per array
#define H1T_OFF_BYTES (W_TOTAL * 2)     // 1376256, 8B-aligned
#define H2T_OFF_BYTES (H1T_OFF_BYTES + HT_WORDS * 8)

__device__ __forceinline__ short f2bf(float f) {
  unsigned u = __builtin_bit_cast(unsigned, f);
  u = u + 0x7fffu + ((u >> 16) & 1u);
  return (short)(u >> 16);
}
__device__ __forceinline__ float fast_sigmoid(float x) {
  return __fdividef(1.0f, 1.0f + __expf(-x));
}
__device__ __forceinline__ float fast_tanh(float x) {
  return 1.0f - __fdividef(2.0f, 1.0f + __expf(2.0f * x));
}
__device__ __forceinline__ short8 cvt8(const float* __restrict__ p) {
  fvec4 lo = *(const fvec4*)p;
  fvec4 hi = *(const fvec4*)(p + 4);
  short8 r;
  r[0] = f2bf(lo[0]); r[1] = f2bf(lo[1]); r[2] = f2bf(lo[2]); r[3] = f2bf(lo[3]);
  r[4] = f2bf(hi[0]); r[5] = f2bf(hi[1]); r[6] = f2bf(hi[2]); r[7] = f2bf(hi[3]);
  return r;
}
__device__ __forceinline__ u64 ld_sc1(const u64* p) {
  return __hip_atomic_load(p, __ATOMIC_RELAXED, __HIP_MEMORY_SCOPE_AGENT);
}
__device__ __forceinline__ void st_sc1(u64* p, u64 v) {
  __hip_atomic_store(p, v, __ATOMIC_RELAXED, __HIP_MEMORY_SCOPE_AGENT);
}

__global__ __launch_bounds__(256) void cvt_weights(
    const float* __restrict__ w0, const float* __restrict__ w1,
    const float* __restrict__ w2, const float* __restrict__ w3,
    short* __restrict__ out) {
  int i = blockIdx.x * 256 + threadIdx.x;
  if (i >= W_TOTAL) return;
  float v;
  if (i < OFF_WHH0)      v = w0[i - OFF_WIH0];
  else if (i < OFF_WIH1) v = w1[i - OFF_WHH0];
  else if (i < OFF_WHH1) v = w2[i - OFF_WIH1];
  else                   v = w3[i - OFF_WHH1];
  out[i] = f2bf(v);
}

__global__ __launch_bounds__(256) void init_state(u64* __restrict__ h1t,
                                                  u64* __restrict__ h2t) {
  int i = blockIdx.x * 256 + threadIdx.x;
  if (i < HT_WORDS) {
    h1t[i] = 0ull;            // h1 init tags never checked (p=0 skips check)
    h2t[i] = (1ull << 32);    // h2t[parity1] read at p=1 expects tag 1, val 0
  }
}

// 256 blocks = (bt 0..15) x (ht 0..15), 384 thr = 6 waves.
// Wave w: layer=w/3, gate=w%3; owns cols [ht*16,ht*16+16); weights in VGPRs.
// Phase p computes h1[p] and h2[p-1]. Cross-block exchange: DATA-EMBEDDED
// READINESS — each h-pair is published as an atomic u64 (tag|2xbf16); waiters
// poll the words they need until tags match (detecting load IS the staging
// load). No flags, no publish drain, no separate stage hop, 2 barriers/step.
// ABA-safe: word written at step p is only rewritten at p+2, which requires
// all peers to have consumed step p (lockstep argument).
__global__ __launch_bounds__(384) void gru_sync(
    const float* __restrict__ x, const short* __restrict__ wb,
    const float* __restrict__ bih0, const float* __restrict__ bhh0,
    const float* __restrict__ bih1, const float* __restrict__ bhh1,
    const float* __restrict__ Wfc, const float* __restrict__ bfc,
    u64* __restrict__ h1t, u64* __restrict__ h2t, float* __restrict__ out) {
  const int tid = threadIdx.x;
  const int lane = tid & 63;
  const int w = tid >> 6;
  const int quad = lane >> 4;
  const int col = lane & 15;
  const int bt = blockIdx.x & 15;
  const int ht = blockIdx.x >> 4;
  const int layer = w / 3, gate = w % 3;
  const int j = ht * 16 + col;
  (void)lane;

  __shared__ __align__(16) short ldsA[2][16][LDH];  // [0]=h1[p-1], [1]=h2[p-2]
  __shared__ __align__(16) float gt[2][6][16][20];  // [0]=IH acc, [1]=HH acc

  // ---- weights -> VGPRs (wave-uniform role) ----
  const short* wih = wb + (layer ? OFF_WIH1 : OFF_WIH0);
  const short* whh = wb + (layer ? OFF_WHH1 : OFF_WHH0);
  short8 wfI[8], wfH[8];
  if (layer == 0) {
#pragma unroll
    for (int f = 0; f < 4; ++f)
      wfI[f] = *(const short8*)(wih + (gate * HH + j) * II + f * 32 + quad * 8);
#pragma unroll
    for (int f = 4; f < 8; ++f) wfI[f] = short8{0, 0, 0, 0, 0, 0, 0, 0};
  } else {
#pragma unroll
    for (int f = 0; f < 8; ++f)
      wfI[f] = *(const short8*)(wih + (gate * HH + j) * HH + f * 32 + quad * 8);
  }
#pragma unroll
  for (int f = 0; f < 8; ++f)
    wfH[f] = *(const short8*)(whh + (gate * HH + j) * HH + f * 32 + quad * 8);

  const float* bihL = layer ? bih1 : bih0;
  const float* bhhL = layer ? bhh1 : bhh0;
  float bI, bH;
  if (gate == 2) { bI = bihL[2 * HH + j]; bH = bhhL[2 * HH + j]; }
  else { bI = bihL[gate * HH + j] + bhhL[gate * HH + j]; bH = 0.f; }

  // ---- elementwise roles: 2 adjacent cols per thread, stable over phases ----
  float h1a = 0.f, h1b = 0.f, h2a = 0.f, h2b = 0.f;
  const int r1 = tid >> 3, c1 = (tid & 7) * 2;                  // tid < 128
  const int r2 = (tid - 256) >> 3;                              // tid >= 256
  const int c2 = ((tid - 256) & 7) * 2;

  const int tilebase = bt * 16 * (HH / 2);  // 2048 words per tile

  for (int p = 0; p <= TT; ++p) {
    // x prefetch (independent of peers; L2-cached normal loads)
    short8 ax[4];
    if (w < 3 && p < TT) {
      const float* xr = x + ((size_t)p * BB + bt * 16 + col) * II + quad * 8;
#pragma unroll
      for (int f = 0; f < 4; ++f) ax[f] = cvt8(xr + f * 32);
    }

    // ---- fused poll + stage: load tagged words until tags == p ----
    u64 w1[8], w2[8];
    {
      const u64* s1w = h1t + ((p + 1) & 1) * HPAR + tilebase;
      const u64* s2w = h2t + (p & 1) * HPAR + tilebase;
      const unsigned tg = (unsigned)p;
      int guard = 0;
      for (;;) {
        bool ok = true;
        if (tid < 256) {
#pragma unroll
          for (int k = 0; k < 8; ++k) w1[k] = ld_sc1(s1w + tid * 8 + k);
#pragma unroll
          for (int k = 0; k < 8; ++k) ok &= ((unsigned)(w1[k] >> 32) == tg);
        }
        if (tid >= 128) {
          const int ti = tid - 128;
#pragma unroll
          for (int k = 0; k < 8; ++k) w2[k] = ld_sc1(s2w + ti * 8 + k);
#pragma unroll
          for (int k = 0; k < 8; ++k) ok &= ((unsigned)(w2[k] >> 32) == tg);
        }
        if (p == 0 || __all(ok) || ++guard > (1 << 16)) break;
      }
    }
    // LDS writes (strip tags, pack 2 words -> one u64 of 4 shorts)
    {
      u64* d1 = (u64*)&ldsA[0][0][0];
      u64* d2 = (u64*)&ldsA[1][0][0];
      if (tid < 256) {
#pragma unroll
        for (int qq = 0; qq < 4; ++qq) {
          u64 v = (w1[2 * qq] & 0xffffffffull) | (w1[2 * qq + 1] << 32);
          int i = tid * 4 + qq, row = i >> 6, c = i & 63;
          d1[row * (LDH / 4) + c] = v;
        }
      }
      if (tid >= 128) {
        const int ti = tid - 128;
#pragma unroll
        for (int qq = 0; qq < 4; ++qq) {
          u64 v = (w2[2 * qq] & 0xffffffffull) | (w2[2 * qq + 1] << 32);
          int i = ti * 4 + qq, row = i >> 6, c = i & 63;
          d2[row * (LDH / 4) + c] = v;
        }
      }
    }
    __syncthreads();  // A: staging complete before MFMA reads

    // ---- MFMA (weights in regs, A frags from LDS) ----
    floatx4 aI = floatx4{bI, bI, bI, bI};
    floatx4 aH = floatx4{bH, bH, bH, bH};
    const short* a1 = &ldsA[0][col][0];
    const short* a2 = &ldsA[1][col][0];
    if (layer == 0) {
      if (p < TT) {
#pragma unroll
        for (int f = 0; f < 4; ++f)
          aI = __builtin_amdgcn_mfma_f32_16x16x32_bf16(ax[f], wfI[f], aI, 0, 0, 0);
      }
#pragma unroll
      for (int f = 0; f < 8; ++f) {
        short8 a = *(const short8*)(a1 + f * 32 + quad * 8);
        aH = __builtin_amdgcn_mfma_f32_16x16x32_bf16(a, wfH[f], aH, 0, 0, 0);
      }
    } else {
#pragma unroll
      for (int f = 0; f < 8; ++f) {
        short8 a = *(const short8*)(a1 + f * 32 + quad * 8);
        aI = __builtin_amdgcn_mfma_f32_16x16x32_bf16(a, wfI[f], aI, 0, 0, 0);
      }
#pragma unroll
      for (int f = 0; f < 8; ++f) {
        short8 a = *(const short8*)(a2 + f * 32 + quad * 8);
        aH = __builtin_amdgcn_mfma_f32_16x16x32_bf16(a, wfH[f], aH, 0, 0, 0);
      }
    }
#pragma unroll
    for (int i = 0; i < 4; ++i) {
      gt[0][w][quad * 4 + i][col] = aI[i];
      gt[1][w][quad * 4 + i][col] = aH[i];
    }
    __syncthreads();  // B: gt complete before elementwise reads

    // ---- elementwise + tagged publish (no barrier, no flag, no drain) ----
    if (tid < 128 && p < TT) {
      float rA = fast_sigmoid(gt[0][0][r1][c1] + gt[1][0][r1][c1]);
      float zA = fast_sigmoid(gt[0][1][r1][c1] + gt[1][1][r1][c1]);
      float nA = fast_tanh(gt[0][2][r1][c1] + rA * gt[1][2][r1][c1]);
      h1a = nA + zA * (h1a - nA);
      float rB = fast_sigmoid(gt[0][0][r1][c1 + 1] + gt[1][0][r1][c1 + 1]);
      float zB = fast_sigmoid(gt[0][1][r1][c1 + 1] + gt[1][1][r1][c1 + 1]);
      float nB = fast_tanh(gt[0][2][r1][c1 + 1] + rB * gt[1][2][r1][c1 + 1]);
      h1b = nB + zB * (h1b - nB);
      unsigned val = ((unsigned)(unsigned short)f2bf(h1b) << 16) |
                     (unsigned)(unsigned short)f2bf(h1a);
      u64 pk = (u64)val | ((u64)(unsigned)(p + 1) << 32);
      u64* dst = h1t + (p & 1) * HPAR + (bt * 16 + r1) * (HH / 2) + ht * 8 + (tid & 7);
      st_sc1(dst, pk);
    }
    if (tid >= 256 && p > 0) {
      float rA = fast_sigmoid(gt[0][3][r2][c2] + gt[1][3][r2][c2]);
      float zA = fast_sigmoid(gt[0][4][r2][c2] + gt[1][4][r2][c2]);
      float nA = fast_tanh(gt[0][5][r2][c2] + rA * gt[1][5][r2][c2]);
      h2a = nA + zA * (h2a - nA);
      float rB = fast_sigmoid(gt[0][3][r2][c2 + 1] + gt[1][3][r2][c2 + 1]);
      float zB = fast_sigmoid(gt[0][4][r2][c2 + 1] + gt[1][4][r2][c2 + 1]);
      float nB = fast_tanh(gt[0][5][r2][c2 + 1] + rB * gt[1][5][r2][c2 + 1]);
      h2b = nB + zB * (h2b - nB);
      unsigned val = ((unsigned)(unsigned short)f2bf(h2b) << 16) |
                     (unsigned)(unsigned short)f2bf(h2a);
      u64 pk = (u64)val | ((u64)(unsigned)(p + 1) << 32);
      u64* dst = h2t + ((p + 1) & 1) * HPAR + (bt * 16 + r2) * (HH / 2) + ht * 8 +
                 ((tid - 256) & 7);
      st_sc1(dst, pk);
    }
    // no post-publish barrier: next-iteration barrier A provides the
    // block-wide convergence; peers detect our words by their tags.
  }

  // ---- FC epilogue: poll h2[TT-1] (tag TT+1, parity 1), then MFMA ----
  {
    const u64* sw = h2t + 1 * HPAR + tilebase;
    u64 wf[8];
    const unsigned tg = (unsigned)(TT + 1);
    int guard = 0;
    for (;;) {
      bool ok = true;
      if (tid < 256) {
#pragma unroll
        for (int k = 0; k < 8; ++k) wf[k] = ld_sc1(sw + tid * 8 + k);
#pragma unroll
        for (int k = 0; k < 8; ++k) ok &= ((unsigned)(wf[k] >> 32) == tg);
      }
      if (__all(ok) || ++guard > (1 << 16)) break;
    }
    u64* d1 = (u64*)&ldsA[0][0][0];
    if (tid < 256) {
#pragma unroll
      for (int qq = 0; qq < 4; ++qq) {
        u64 v = (wf[2 * qq] & 0xffffffffull) | (wf[2 * qq + 1] << 32);
        int i = tid * 4 + qq, row = i >> 6, c = i & 63;
        d1[row * (LDH / 4) + c] = v;
      }
    }
  }
  __syncthreads();
  if (w == 0) {
    float bbv = bfc[j];
    floatx4 acc = floatx4{bbv, bbv, bbv, bbv};
#pragma unroll
    for (int f = 0; f < 8; ++f) {
      short8 a = *(const short8*)(&ldsA[0][col][0] + f * 32 + quad * 8);
      short8 bfrag = cvt8(Wfc + j * HH + f * 32 + quad * 8);
      acc = __builtin_amdgcn_mfma_f32_16x16x32_bf16(a, bfrag, acc, 0, 0, 0);
    }
#pragma unroll
    for (int i = 0; i < 4; ++i)
      out[(size_t)(bt * 16 + quad * 4 + i) * HH + j] = acc[i];
  }
}

extern "C" void kernel_launch(void* const* d_in, const int* in_sizes, int n_in,
                              void* d_out, int out_size, void* d_ws,
                              size_t ws_size, hipStream_t stream) {
  const float* x = (const float*)d_in[0];
  const float* Wih0 = (const float*)d_in[1];
  const float* Whh0 = (const float*)d_in[2];
  const float* bih0 = (const float*)d_in[3];
  const float* bhh0 = (const float*)d_in[4];
  const float* Wih1 = (const float*)d_in[5];
  const float* Whh1 = (const float*)d_in[6];
  const float* bih1 = (const float*)d_in[7];
  const float* bhh1 = (const float*)d_in[8];
  const float* Wfc = (const float*)d_in[9];
  const float* bfc = (const float*)d_in[10];

  short* wb = (short*)d_ws;
  u64* h1t = (u64*)((char*)d_ws + H1T_OFF_BYTES);
  u64* h2t = (u64*)((char*)d_ws + H2T_OFF_BYTES);

  cvt_weights<<<(W_TOTAL + 255) / 256, 256, 0, stream>>>(Wih0, Whh0, Wih1, Whh1, wb);
  init_state<<<(HT_WORDS + 255) / 256, 256, 0, stream>>>(h1t, h2t);
  gru_sync<<<256, 384, 0, stream>>>(x, wb, bih0, bhh0, bih1, bhh1, Wfc, bfc,
                                    h1t, h2t, (float*)d_out);
}

// Round 8
// 2093.092 us; speedup vs baseline: 3.0285x; 1.3956x over previous
//
#include <hip/hip_runtime.h>

#define TT 512
#define BB 256
#define II 128
#define HH 256

typedef __attribute__((ext_vector_type(8))) short short8;
typedef __attribute__((ext_vector_type(4))) float floatx4;
typedef __attribute__((ext_vector_type(4))) float fvec4;
typedef unsigned long long u64;

// ws layout (shorts): bf16 weights, h1g[2][B][H], h2g[2][B][H], then flags.
#define OFF_WIH0 0
#define OFF_WHH0 (OFF_WIH0 + 3 * HH * II)
#define OFF_WIH1 (OFF_WHH0 + 3 * HH * HH)
#define OFF_WHH1 (OFF_WIH1 + 3 * HH * HH)
#define W_TOTAL (OFF_WHH1 + 3 * HH * HH)
#define H1G_OFF W_TOTAL
#define H2G_OFF (H1G_OFF + 2 * BB * HH)
#define WS_SHORTS (H2G_OFF + 2 * BB * HH)
#define FLAGS_OFF_BYTES (WS_SHORTS * 2)
#define FLAG_STRIDE 32   // uints; 16 flags per line; h1fl lines 0-15, h2fl 16-31
#define HPARW (BB * HH / 4)  // u64 words per parity buffer = 16384

struct U64x2 { u64 lo, hi; };

__device__ __forceinline__ short f2bf(float f) {
  unsigned u = __builtin_bit_cast(unsigned, f);
  u = u + 0x7fffu + ((u >> 16) & 1u);
  return (short)(u >> 16);
}
__device__ __forceinline__ float fast_sigmoid(float x) {
  return __fdividef(1.0f, 1.0f + __expf(-x));
}
__device__ __forceinline__ float fast_tanh(float x) {
  return 1.0f - __fdividef(2.0f, 1.0f + __expf(2.0f * x));
}
__device__ __forceinline__ short8 cvt8(const float* __restrict__ p) {
  fvec4 lo = *(const fvec4*)p;
  fvec4 hi = *(const fvec4*)(p + 4);
  short8 r;
  r[0] = f2bf(lo[0]); r[1] = f2bf(lo[1]); r[2] = f2bf(lo[2]); r[3] = f2bf(lo[3]);
  r[4] = f2bf(hi[0]); r[5] = f2bf(hi[1]); r[6] = f2bf(hi[2]); r[7] = f2bf(hi[3]);
  return r;
}
__device__ __forceinline__ u64 ld_sc1(const u64* p) {
  return __hip_atomic_load(p, __ATOMIC_RELAXED, __HIP_MEMORY_SCOPE_AGENT);
}
__device__ __forceinline__ unsigned ld_flag(const unsigned* p) {
  return __hip_atomic_load(p, __ATOMIC_RELAXED, __HIP_MEMORY_SCOPE_AGENT);
}
__device__ __forceinline__ void st_flag(unsigned* p, unsigned v) {
  __hip_atomic_store(p, v, __ATOMIC_RELAXED, __HIP_MEMORY_SCOPE_AGENT);
}
__device__ __forceinline__ void st_h(unsigned short* p, unsigned short v) {
  __hip_atomic_store(p, v, __ATOMIC_RELAXED, __HIP_MEMORY_SCOPE_AGENT);
}
#define DRAIN_VMEM asm volatile("s_waitcnt vmcnt(0)" ::: "memory")

__global__ __launch_bounds__(256) void cvt_weights(
    const float* __restrict__ w0, const float* __restrict__ w1,
    const float* __restrict__ w2, const float* __restrict__ w3,
    short* __restrict__ out) {
  int i = blockIdx.x * 256 + threadIdx.x;
  if (i >= W_TOTAL) return;
  float v;
  if (i < OFF_WHH0)      v = w0[i - OFF_WIH0];
  else if (i < OFF_WIH1) v = w1[i - OFF_WHH0];
  else if (i < OFF_WHH1) v = w2[i - OFF_WIH1];
  else                   v = w3[i - OFF_WHH1];
  out[i] = f2bf(v);
}

__global__ __launch_bounds__(256) void init_state(unsigned* __restrict__ hz,
                                                  unsigned* __restrict__ flags) {
  int i = blockIdx.x * 256 + threadIdx.x;
  if (i < 2 * BB * HH) hz[i] = 0u;  // h1g+h2g = 4*B*H shorts = 2*B*H uints
  if (i < 32 * FLAG_STRIDE) flags[i] = 0u;
}

// 512 blocks x 64 threads: bid = layer*256 + bt*16 + ht. ONE WAVE per block
// owns all 3 gates of (layer, bt-tile, 16-col slice) -> gates of a (row,col)
// live in the SAME lane's accs: no gt LDS, no barriers, no LDS staging (A-
// frags loaded straight to VGPRs via ld_sc1 pairs). Layer chains run on
// separate blocks; 2 blocks/CU hide each other's exchange latency.
// Protocol (R3-proven primitives): publish 2B agent stores -> wave vmcnt(0)
// drain -> per-block flag store; peers poll 64B flag lines then stage once.
// L0@p waits {h1fl>=p, h2fl>=p-1 (backpressure: L1 consumed h1[p-2])};
// L1@q waits {h2fl>=q, h1fl>=q+1}. No circular wait; parity double-buffer.
__global__ __launch_bounds__(64) void gru_sync(
    const float* __restrict__ x, const short* __restrict__ wb,
    const float* __restrict__ bih0, const float* __restrict__ bhh0,
    const float* __restrict__ bih1, const float* __restrict__ bhh1,
    const float* __restrict__ Wfc, const float* __restrict__ bfc,
    short* __restrict__ h1g, short* __restrict__ h2g,
    unsigned* __restrict__ flags, float* __restrict__ out) {
  const int lane = threadIdx.x;
  const int quad = lane >> 4;
  const int col = lane & 15;
  const int bid = blockIdx.x;
  const int layer = bid >> 8;
  const int bt = (bid >> 4) & 15;
  const int ht = bid & 15;
  const int j = ht * 16 + col;

  unsigned* h1fl = flags + bt * FLAG_STRIDE;
  unsigned* h2fl = flags + (16 + bt) * FLAG_STRIDE;
  unsigned* myfl = layer ? h2fl : h1fl;

  // ---- weights -> VGPRs: all 3 gates (B-fragments, col j, k-chunk quad) ----
  const short* wih = wb + (layer ? OFF_WIH1 : OFF_WIH0);
  const short* whh = wb + (layer ? OFF_WHH1 : OFF_WHH0);
  const int KI = layer ? HH : II;       // IH K-dim
  short8 wI0[8], wI1[8], wI2[8], wH0[8], wH1[8], wH2[8];
#pragma unroll
  for (int f = 0; f < 8; ++f) {
    if (f * 32 < KI) {
      wI0[f] = *(const short8*)(wih + (0 * HH + j) * KI + f * 32 + quad * 8);
      wI1[f] = *(const short8*)(wih + (1 * HH + j) * KI + f * 32 + quad * 8);
      wI2[f] = *(const short8*)(wih + (2 * HH + j) * KI + f * 32 + quad * 8);
    } else {
      wI0[f] = short8{0,0,0,0,0,0,0,0};
      wI1[f] = short8{0,0,0,0,0,0,0,0};
      wI2[f] = short8{0,0,0,0,0,0,0,0};
    }
    wH0[f] = *(const short8*)(whh + (0 * HH + j) * HH + f * 32 + quad * 8);
    wH1[f] = *(const short8*)(whh + (1 * HH + j) * HH + f * 32 + quad * 8);
    wH2[f] = *(const short8*)(whh + (2 * HH + j) * HH + f * 32 + quad * 8);
  }
  const float* bihL = layer ? bih1 : bih0;
  const float* bhhL = layer ? bhh1 : bhh0;
  const float bI0 = bihL[j] + bhhL[j];
  const float bI1 = bihL[HH + j] + bhhL[HH + j];
  const float bI2 = bihL[2 * HH + j];
  const float bH2 = bhhL[2 * HH + j];

  // recurrent state held in regs: h[bt*16+quad*4+i][j] for i=0..3
  float hprev0 = 0.f, hprev1 = 0.f, hprev2 = 0.f, hprev3 = 0.f;

  const u64* h1w = (const u64*)h1g;
  const u64* h2w = (const u64*)h2g;
  const int rowW = (bt * 16 + col) * 64;  // u64 words per h row = HH*2/8

  for (int p = 0; p < TT; ++p) {
    // x prefetch (L0 only; plain cached loads, read-only input)
    short8 ax[4];
    if (layer == 0) {
      const float* xr = x + ((size_t)p * BB + bt * 16 + col) * II + quad * 8;
#pragma unroll
      for (int f = 0; f < 4; ++f) ax[f] = cvt8(xr + f * 32);
    }

    // ---- poll (64B flag lines; lanes 0-15 primary, 16-31 secondary) ----
    {
      unsigned tgt = 0;
      const unsigned* fp = h1fl;
      if (layer == 0) {
        if (lane < 16)      { tgt = (unsigned)p; fp = h1fl + lane; }
        else if (lane < 32) { tgt = (p >= 1) ? (unsigned)(p - 1) : 0u; fp = h2fl + (lane - 16); }
      } else {
        if (lane < 16)      { tgt = (unsigned)p; fp = h2fl + lane; }
        else if (lane < 32) { tgt = (unsigned)(p + 1); fp = h1fl + (lane - 16); }
      }
      if (layer == 1 || p > 0) {
        int guard = 0;
        for (;;) {
          unsigned v = ld_flag(fp);
          if (__all(v >= tgt) || ++guard > (1 << 20)) break;
        }
      }
    }

    // ---- stage A-fragments straight to VGPRs (ld_sc1 pairs, proven path) ----
    short8 a1[8], a2[8];
    if (layer == 0) {
      const u64* s1 = h1w + ((p + 1) & 1) * HPARW + rowW;  // h1[p-1]
#pragma unroll
      for (int f = 0; f < 8; ++f) {
        u64 lo = ld_sc1(s1 + f * 8 + quad * 2);
        u64 hi = ld_sc1(s1 + f * 8 + quad * 2 + 1);
        a1[f] = __builtin_bit_cast(short8, U64x2{lo, hi});
      }
    } else {
      const u64* s1 = h1w + (p & 1) * HPARW + rowW;        // h1[p]
      const u64* s2 = h2w + ((p + 1) & 1) * HPARW + rowW;  // h2[p-1]
#pragma unroll
      for (int f = 0; f < 8; ++f) {
        u64 lo = ld_sc1(s1 + f * 8 + quad * 2);
        u64 hi = ld_sc1(s1 + f * 8 + quad * 2 + 1);
        a1[f] = __builtin_bit_cast(short8, U64x2{lo, hi});
      }
#pragma unroll
      for (int f = 0; f < 8; ++f) {
        u64 lo = ld_sc1(s2 + f * 8 + quad * 2);
        u64 hi = ld_sc1(s2 + f * 8 + quad * 2 + 1);
        a2[f] = __builtin_bit_cast(short8, U64x2{lo, hi});
      }
    }

    // ---- MFMA: all 3 gates in this wave's accs ----
    floatx4 aR = floatx4{bI0, bI0, bI0, bI0};
    floatx4 aZ = floatx4{bI1, bI1, bI1, bI1};
    floatx4 aN = floatx4{bI2, bI2, bI2, bI2};
    floatx4 hN = floatx4{bH2, bH2, bH2, bH2};
    if (layer == 0) {
#pragma unroll
      for (int f = 0; f < 4; ++f) {  // IH: x (K=128)
        aR = __builtin_amdgcn_mfma_f32_16x16x32_bf16(ax[f], wI0[f], aR, 0, 0, 0);
        aZ = __builtin_amdgcn_mfma_f32_16x16x32_bf16(ax[f], wI1[f], aZ, 0, 0, 0);
        aN = __builtin_amdgcn_mfma_f32_16x16x32_bf16(ax[f], wI2[f], aN, 0, 0, 0);
      }
#pragma unroll
      for (int f = 0; f < 8; ++f) {  // HH: h1[p-1]
        aR = __builtin_amdgcn_mfma_f32_16x16x32_bf16(a1[f], wH0[f], aR, 0, 0, 0);
        aZ = __builtin_amdgcn_mfma_f32_16x16x32_bf16(a1[f], wH1[f], aZ, 0, 0, 0);
        hN = __builtin_amdgcn_mfma_f32_16x16x32_bf16(a1[f], wH2[f], hN, 0, 0, 0);
      }
    } else {
#pragma unroll
      for (int f = 0; f < 8; ++f) {  // IH: h1[p]
        aR = __builtin_amdgcn_mfma_f32_16x16x32_bf16(a1[f], wI0[f], aR, 0, 0, 0);
        aZ = __builtin_amdgcn_mfma_f32_16x16x32_bf16(a1[f], wI1[f], aZ, 0, 0, 0);
        aN = __builtin_amdgcn_mfma_f32_16x16x32_bf16(a1[f], wI2[f], aN, 0, 0, 0);
      }
#pragma unroll
      for (int f = 0; f < 8; ++f) {  // HH: h2[p-1]
        aR = __builtin_amdgcn_mfma_f32_16x16x32_bf16(a2[f], wH0[f], aR, 0, 0, 0);
        aZ = __builtin_amdgcn_mfma_f32_16x16x32_bf16(a2[f], wH1[f], aZ, 0, 0, 0);
        hN = __builtin_amdgcn_mfma_f32_16x16x32_bf16(a2[f], wH2[f], hN, 0, 0, 0);
      }
    }

    // ---- elementwise from own accs + publish (2B agent stores) ----
    short* hout = (layer ? h2g : h1g) + (p & 1) * BB * HH;
    unsigned short* dst = (unsigned short*)hout +
                          (size_t)(bt * 16 + quad * 4) * HH + j;
    {
      float r0 = fast_sigmoid(aR[0]), z0 = fast_sigmoid(aZ[0]);
      float n0 = fast_tanh(aN[0] + r0 * hN[0]);
      hprev0 = n0 + z0 * (hprev0 - n0);
      st_h(dst + 0 * HH, (unsigned short)f2bf(hprev0));
      float r1 = fast_sigmoid(aR[1]), z1 = fast_sigmoid(aZ[1]);
      float n1 = fast_tanh(aN[1] + r1 * hN[1]);
      hprev1 = n1 + z1 * (hprev1 - n1);
      st_h(dst + 1 * HH, (unsigned short)f2bf(hprev1));
      float r2 = fast_sigmoid(aR[2]), z2 = fast_sigmoid(aZ[2]);
      float n2 = fast_tanh(aN[2] + r2 * hN[2]);
      hprev2 = n2 + z2 * (hprev2 - n2);
      st_h(dst + 2 * HH, (unsigned short)f2bf(hprev2));
      float r3 = fast_sigmoid(aR[3]), z3 = fast_sigmoid(aZ[3]);
      float n3 = fast_tanh(aN[3] + r3 * hN[3]);
      hprev3 = n3 + z3 * (hprev3 - n3);
      st_h(dst + 3 * HH, (unsigned short)f2bf(hprev3));
    }
    DRAIN_VMEM;  // wave-local: all 64 lanes' publishes acked at coherence point
    if (lane == 0) st_flag(myfl + ht, (unsigned)(p + 1));
  }

  // ---- FC epilogue (layer-1 blocks): out = h2[TT-1] @ Wfc^T + bfc ----
  if (layer == 1) {
    {
      int guard = 0;
      for (;;) {
        unsigned v = (lane < 16) ? ld_flag(h2fl + lane) : (unsigned)TT;
        if (__all(v >= (unsigned)TT) || ++guard > (1 << 20)) break;
      }
    }
    const u64* s2 = h2w + ((TT - 1) & 1) * HPARW + rowW;  // parity 1
    float bbv = bfc[j];
    floatx4 acc = floatx4{bbv, bbv, bbv, bbv};
#pragma unroll
    for (int f = 0; f < 8; ++f) {
      u64 lo = ld_sc1(s2 + f * 8 + quad * 2);
      u64 hi = ld_sc1(s2 + f * 8 + quad * 2 + 1);
      short8 a = __builtin_bit_cast(short8, U64x2{lo, hi});
      short8 bfrag = cvt8(Wfc + j * HH + f * 32 + quad * 8);
      acc = __builtin_amdgcn_mfma_f32_16x16x32_bf16(a, bfrag, acc, 0, 0, 0);
    }
#pragma unroll
    for (int i = 0; i < 4; ++i)
      out[(size_t)(bt * 16 + quad * 4 + i) * HH + j] = acc[i];
  }
}

extern "C" void kernel_launch(void* const* d_in, const int* in_sizes, int n_in,
                              void* d_out, int out_size, void* d_ws,
                              size_t ws_size, hipStream_t stream) {
  const float* x = (const float*)d_in[0];
  const float* Wih0 = (const float*)d_in[1];
  const float* Whh0 = (const float*)d_in[2];
  const float* bih0 = (const float*)d_in[3];
  const float* bhh0 = (const float*)d_in[4];
  const float* Wih1 = (const float*)d_in[5];
  const float* Whh1 = (const float*)d_in[6];
  const float* bih1 = (const float*)d_in[7];
  const float* bhh1 = (const float*)d_in[8];
  const float* Wfc = (const float*)d_in[9];
  const float* bfc = (const float*)d_in[10];

  short* wb = (short*)d_ws;
  short* h1g = wb + H1G_OFF;
  short* h2g = wb + H2G_OFF;
  unsigned* flags = (unsigned*)((char*)d_ws + FLAGS_OFF_BYTES);
  unsigned* hz = (unsigned*)(wb + H1G_OFF);

  cvt_weights<<<(W_TOTAL + 255) / 256, 256, 0, stream>>>(Wih0, Whh0, Wih1, Whh1, wb);
  init_state<<<(2 * BB * HH + 255) / 256, 256, 0, stream>>>(hz, flags);
  gru_sync<<<512, 64, 0, stream>>>(x, wb, bih0, bhh0, bih1, bhh1, Wfc, bfc,
                                   h1g, h2g, flags, (float*)d_out);
}

// Round 9
// 2056.137 us; speedup vs baseline: 3.0829x; 1.0180x over previous
//
#include <hip/hip_runtime.h>

#define TT 512
#define BB 256
#define II 128
#define HH 256

typedef __attribute__((ext_vector_type(8))) short short8;
typedef __attribute__((ext_vector_type(4))) float floatx4;
typedef __attribute__((ext_vector_type(4))) float fvec4;
typedef unsigned long long u64;

// ws layout (shorts): bf16 weights, h1g[2][B][H], h2g[2][B][H], then flags.
#define OFF_WIH0 0
#define OFF_WHH0 (OFF_WIH0 + 3 * HH * II)
#define OFF_WIH1 (OFF_WHH0 + 3 * HH * HH)
#define OFF_WHH1 (OFF_WIH1 + 3 * HH * HH)
#define W_TOTAL (OFF_WHH1 + 3 * HH * HH)
#define H1G_OFF W_TOTAL
#define H2G_OFF (H1G_OFF + 2 * BB * HH)
#define WS_SHORTS (H2G_OFF + 2 * BB * HH)
#define FLAGS_OFF_BYTES (WS_SHORTS * 2)
#define FLAG_STRIDE 32   // uints; 16 flags per line; h1fl lines 0-15, h2fl 16-31
#define HPARW (BB * HH / 4)  // u64 words per parity buffer = 16384

struct U64x2 { u64 lo, hi; };

__device__ __forceinline__ short f2bf(float f) {
  unsigned u = __builtin_bit_cast(unsigned, f);
  u = u + 0x7fffu + ((u >> 16) & 1u);
  return (short)(u >> 16);
}
__device__ __forceinline__ float fast_sigmoid(float x) {
  return __fdividef(1.0f, 1.0f + __expf(-x));
}
__device__ __forceinline__ float fast_tanh(float x) {
  return 1.0f - __fdividef(2.0f, 1.0f + __expf(2.0f * x));
}
__device__ __forceinline__ short8 cvt8(const float* __restrict__ p) {
  fvec4 lo = *(const fvec4*)p;
  fvec4 hi = *(const fvec4*)(p + 4);
  short8 r;
  r[0] = f2bf(lo[0]); r[1] = f2bf(lo[1]); r[2] = f2bf(lo[2]); r[3] = f2bf(lo[3]);
  r[4] = f2bf(hi[0]); r[5] = f2bf(hi[1]); r[6] = f2bf(hi[2]); r[7] = f2bf(hi[3]);
  return r;
}
__device__ __forceinline__ u64 ld_sc1(const u64* p) {
  return __hip_atomic_load(p, __ATOMIC_RELAXED, __HIP_MEMORY_SCOPE_AGENT);
}
__device__ __forceinline__ unsigned ld_flag(const unsigned* p) {
  return __hip_atomic_load(p, __ATOMIC_RELAXED, __HIP_MEMORY_SCOPE_AGENT);
}
__device__ __forceinline__ void st_flag(unsigned* p, unsigned v) {
  __hip_atomic_store(p, v, __ATOMIC_RELAXED, __HIP_MEMORY_SCOPE_AGENT);
}
__device__ __forceinline__ void st_h(unsigned short* p, unsigned short v) {
  __hip_atomic_store(p, v, __ATOMIC_RELAXED, __HIP_MEMORY_SCOPE_AGENT);
}
#define DRAIN_VMEM asm volatile("s_waitcnt vmcnt(0)" ::: "memory")

__global__ __launch_bounds__(256) void cvt_weights(
    const float* __restrict__ w0, const float* __restrict__ w1,
    const float* __restrict__ w2, const float* __restrict__ w3,
    short* __restrict__ out) {
  int i = blockIdx.x * 256 + threadIdx.x;
  if (i >= W_TOTAL) return;
  float v;
  if (i < OFF_WHH0)      v = w0[i - OFF_WIH0];
  else if (i < OFF_WIH1) v = w1[i - OFF_WHH0];
  else if (i < OFF_WHH1) v = w2[i - OFF_WIH1];
  else                   v = w3[i - OFF_WHH1];
  out[i] = f2bf(v);
}

__global__ __launch_bounds__(256) void init_state(unsigned* __restrict__ hz,
                                                  unsigned* __restrict__ flags) {
  int i = blockIdx.x * 256 + threadIdx.x;
  if (i < 2 * BB * HH) hz[i] = 0u;  // h1g+h2g = 4*B*H shorts = 2*B*H uints
  if (i < 32 * FLAG_STRIDE) flags[i] = 0u;
}

// 512 blocks x 64 threads: bid = layer*256 + ht*16 + bt.
// XCD PLACEMENT (the R8 lesson): round-robin dispatch puts block bid on XCD
// bid%8 = bt%8 -> all 16 ht-blocks of a bt group, BOTH layers, share one XCD.
// The whole h exchange is then XCD-local L2 traffic (R8's ht-scattered
// mapping pushed it cross-XCD: FETCH 105->802 MB, hops at L3 latency).
// ONE WAVE per block owns all 3 gates of (layer, bt-tile, 16-col slice):
// gates of a (row,col) live in the same lane's accs -> no gt LDS, no
// barriers, no LDS staging (A-frags loaded straight to VGPRs via ld_sc1).
// Protocol (R3-proven primitives): publish 2B agent stores -> wave vmcnt(0)
// drain -> per-block flag store; peers poll 64B flag lines then stage once.
// L0@p waits {h1fl>=p, h2fl>=p-1 (backpressure: L1 consumed h1[p-2])};
// L1@q waits {h2fl>=q, h1fl>=q+1}. No circular wait; parity double-buffer.
__global__ __launch_bounds__(64) void gru_sync(
    const float* __restrict__ x, const short* __restrict__ wb,
    const float* __restrict__ bih0, const float* __restrict__ bhh0,
    const float* __restrict__ bih1, const float* __restrict__ bhh1,
    const float* __restrict__ Wfc, const float* __restrict__ bfc,
    short* __restrict__ h1g, short* __restrict__ h2g,
    unsigned* __restrict__ flags, float* __restrict__ out) {
  const int lane = threadIdx.x;
  const int quad = lane >> 4;
  const int col = lane & 15;
  const int bid = blockIdx.x;
  const int layer = bid >> 8;
  const int bt = bid & 15;          // XCD = bt%8 for both layers
  const int ht = (bid >> 4) & 15;
  const int j = ht * 16 + col;

  unsigned* h1fl = flags + bt * FLAG_STRIDE;
  unsigned* h2fl = flags + (16 + bt) * FLAG_STRIDE;
  unsigned* myfl = layer ? h2fl : h1fl;

  // ---- weights -> VGPRs: all 3 gates (B-fragments, col j, k-chunk quad) ----
  const short* wih = wb + (layer ? OFF_WIH1 : OFF_WIH0);
  const short* whh = wb + (layer ? OFF_WHH1 : OFF_WHH0);
  const int KI = layer ? HH : II;       // IH K-dim
  short8 wI0[8], wI1[8], wI2[8], wH0[8], wH1[8], wH2[8];
#pragma unroll
  for (int f = 0; f < 8; ++f) {
    if (f * 32 < KI) {
      wI0[f] = *(const short8*)(wih + (0 * HH + j) * KI + f * 32 + quad * 8);
      wI1[f] = *(const short8*)(wih + (1 * HH + j) * KI + f * 32 + quad * 8);
      wI2[f] = *(const short8*)(wih + (2 * HH + j) * KI + f * 32 + quad * 8);
    } else {
      wI0[f] = short8{0,0,0,0,0,0,0,0};
      wI1[f] = short8{0,0,0,0,0,0,0,0};
      wI2[f] = short8{0,0,0,0,0,0,0,0};
    }
    wH0[f] = *(const short8*)(whh + (0 * HH + j) * HH + f * 32 + quad * 8);
    wH1[f] = *(const short8*)(whh + (1 * HH + j) * HH + f * 32 + quad * 8);
    wH2[f] = *(const short8*)(whh + (2 * HH + j) * HH + f * 32 + quad * 8);
  }
  const float* bihL = layer ? bih1 : bih0;
  const float* bhhL = layer ? bhh1 : bhh0;
  const float bI0 = bihL[j] + bhhL[j];
  const float bI1 = bihL[HH + j] + bhhL[HH + j];
  const float bI2 = bihL[2 * HH + j];
  const float bH2 = bhhL[2 * HH + j];

  // recurrent state held in regs: h[bt*16+quad*4+i][j] for i=0..3
  float hprev0 = 0.f, hprev1 = 0.f, hprev2 = 0.f, hprev3 = 0.f;

  const u64* h1w = (const u64*)h1g;
  const u64* h2w = (const u64*)h2g;
  const int rowW = (bt * 16 + col) * 64;  // u64 words per h row = HH*2/8

  for (int p = 0; p < TT; ++p) {
    // x prefetch (L0 only; plain cached loads, read-only input)
    short8 ax[4];
    if (layer == 0) {
      const float* xr = x + ((size_t)p * BB + bt * 16 + col) * II + quad * 8;
#pragma unroll
      for (int f = 0; f < 4; ++f) ax[f] = cvt8(xr + f * 32);
    }

    // ---- poll (64B flag lines; lanes 0-15 primary, 16-31 secondary) ----
    {
      unsigned tgt = 0;
      const unsigned* fp = h1fl;
      if (layer == 0) {
        if (lane < 16)      { tgt = (unsigned)p; fp = h1fl + lane; }
        else if (lane < 32) { tgt = (p >= 1) ? (unsigned)(p - 1) : 0u; fp = h2fl + (lane - 16); }
      } else {
        if (lane < 16)      { tgt = (unsigned)p; fp = h2fl + lane; }
        else if (lane < 32) { tgt = (unsigned)(p + 1); fp = h1fl + (lane - 16); }
      }
      if (layer == 1 || p > 0) {
        int guard = 0;
        for (;;) {
          unsigned v = ld_flag(fp);
          if (__all(v >= tgt) || ++guard > (1 << 20)) break;
        }
      }
    }

    // ---- stage A-fragments straight to VGPRs (ld_sc1 pairs, proven path) ----
    short8 a1[8], a2[8];
    if (layer == 0) {
      const u64* s1 = h1w + ((p + 1) & 1) * HPARW + rowW;  // h1[p-1]
#pragma unroll
      for (int f = 0; f < 8; ++f) {
        u64 lo = ld_sc1(s1 + f * 8 + quad * 2);
        u64 hi = ld_sc1(s1 + f * 8 + quad * 2 + 1);
        a1[f] = __builtin_bit_cast(short8, U64x2{lo, hi});
      }
    } else {
      const u64* s1 = h1w + (p & 1) * HPARW + rowW;        // h1[p]
      const u64* s2 = h2w + ((p + 1) & 1) * HPARW + rowW;  // h2[p-1]
#pragma unroll
      for (int f = 0; f < 8; ++f) {
        u64 lo = ld_sc1(s1 + f * 8 + quad * 2);
        u64 hi = ld_sc1(s1 + f * 8 + quad * 2 + 1);
        a1[f] = __builtin_bit_cast(short8, U64x2{lo, hi});
      }
#pragma unroll
      for (int f = 0; f < 8; ++f) {
        u64 lo = ld_sc1(s2 + f * 8 + quad * 2);
        u64 hi = ld_sc1(s2 + f * 8 + quad * 2 + 1);
        a2[f] = __builtin_bit_cast(short8, U64x2{lo, hi});
      }
    }

    // ---- MFMA: all 3 gates in this wave's accs ----
    floatx4 aR = floatx4{bI0, bI0, bI0, bI0};
    floatx4 aZ = floatx4{bI1, bI1, bI1, bI1};
    floatx4 aN = floatx4{bI2, bI2, bI2, bI2};
    floatx4 hN = floatx4{bH2, bH2, bH2, bH2};
    if (layer == 0) {
#pragma unroll
      for (int f = 0; f < 4; ++f) {  // IH: x (K=128)
        aR = __builtin_amdgcn_mfma_f32_16x16x32_bf16(ax[f], wI0[f], aR, 0, 0, 0);
        aZ = __builtin_amdgcn_mfma_f32_16x16x32_bf16(ax[f], wI1[f], aZ, 0, 0, 0);
        aN = __builtin_amdgcn_mfma_f32_16x16x32_bf16(ax[f], wI2[f], aN, 0, 0, 0);
      }
#pragma unroll
      for (int f = 0; f < 8; ++f) {  // HH: h1[p-1]
        aR = __builtin_amdgcn_mfma_f32_16x16x32_bf16(a1[f], wH0[f], aR, 0, 0, 0);
        aZ = __builtin_amdgcn_mfma_f32_16x16x32_bf16(a1[f], wH1[f], aZ, 0, 0, 0);
        hN = __builtin_amdgcn_mfma_f32_16x16x32_bf16(a1[f], wH2[f], hN, 0, 0, 0);
      }
    } else {
#pragma unroll
      for (int f = 0; f < 8; ++f) {  // IH: h1[p]
        aR = __builtin_amdgcn_mfma_f32_16x16x32_bf16(a1[f], wI0[f], aR, 0, 0, 0);
        aZ = __builtin_amdgcn_mfma_f32_16x16x32_bf16(a1[f], wI1[f], aZ, 0, 0, 0);
        aN = __builtin_amdgcn_mfma_f32_16x16x32_bf16(a1[f], wI2[f], aN, 0, 0, 0);
      }
#pragma unroll
      for (int f = 0; f < 8; ++f) {  // HH: h2[p-1]
        aR = __builtin_amdgcn_mfma_f32_16x16x32_bf16(a2[f], wH0[f], aR, 0, 0, 0);
        aZ = __builtin_amdgcn_mfma_f32_16x16x32_bf16(a2[f], wH1[f], aZ, 0, 0, 0);
        hN = __builtin_amdgcn_mfma_f32_16x16x32_bf16(a2[f], wH2[f], hN, 0, 0, 0);
      }
    }

    // ---- elementwise from own accs + publish (2B agent stores) ----
    short* hout = (layer ? h2g : h1g) + (p & 1) * BB * HH;
    unsigned short* dst = (unsigned short*)hout +
                          (size_t)(bt * 16 + quad * 4) * HH + j;
    {
      float r0 = fast_sigmoid(aR[0]), z0 = fast_sigmoid(aZ[0]);
      float n0 = fast_tanh(aN[0] + r0 * hN[0]);
      hprev0 = n0 + z0 * (hprev0 - n0);
      st_h(dst + 0 * HH, (unsigned short)f2bf(hprev0));
      float r1 = fast_sigmoid(aR[1]), z1 = fast_sigmoid(aZ[1]);
      float n1 = fast_tanh(aN[1] + r1 * hN[1]);
      hprev1 = n1 + z1 * (hprev1 - n1);
      st_h(dst + 1 * HH, (unsigned short)f2bf(hprev1));
      float r2 = fast_sigmoid(aR[2]), z2 = fast_sigmoid(aZ[2]);
      float n2 = fast_tanh(aN[2] + r2 * hN[2]);
      hprev2 = n2 + z2 * (hprev2 - n2);
      st_h(dst + 2 * HH, (unsigned short)f2bf(hprev2));
      float r3 = fast_sigmoid(aR[3]), z3 = fast_sigmoid(aZ[3]);
      float n3 = fast_tanh(aN[3] + r3 * hN[3]);
      hprev3 = n3 + z3 * (hprev3 - n3);
      st_h(dst + 3 * HH, (unsigned short)f2bf(hprev3));
    }
    DRAIN_VMEM;  // wave-local: all 64 lanes' publishes acked at coherence point
    if (lane == 0) st_flag(myfl + ht, (unsigned)(p + 1));
  }

  // ---- FC epilogue (layer-1 blocks): out = h2[TT-1] @ Wfc^T + bfc ----
  if (layer == 1) {
    {
      int guard = 0;
      for (;;) {
        unsigned v = (lane < 16) ? ld_flag(h2fl + lane) : (unsigned)TT;
        if (__all(v >= (unsigned)TT) || ++guard > (1 << 20)) break;
      }
    }
    const u64* s2 = h2w + ((TT - 1) & 1) * HPARW + rowW;  // parity 1
    float bbv = bfc[j];
    floatx4 acc = floatx4{bbv, bbv, bbv, bbv};
#pragma unroll
    for (int f = 0; f < 8; ++f) {
      u64 lo = ld_sc1(s2 + f * 8 + quad * 2);
      u64 hi = ld_sc1(s2 + f * 8 + quad * 2 + 1);
      short8 a = __builtin_bit_cast(short8, U64x2{lo, hi});
      short8 bfrag = cvt8(Wfc + j * HH + f * 32 + quad * 8);
      acc = __builtin_amdgcn_mfma_f32_16x16x32_bf16(a, bfrag, acc, 0, 0, 0);
    }
#pragma unroll
    for (int i = 0; i < 4; ++i)
      out[(size_t)(bt * 16 + quad * 4 + i) * HH + j] = acc[i];
  }
}

extern "C" void kernel_launch(void* const* d_in, const int* in_sizes, int n_in,
                              void* d_out, int out_size, void* d_ws,
                              size_t ws_size, hipStream_t stream) {
  const float* x = (const float*)d_in[0];
  const float* Wih0 = (const float*)d_in[1];
  const float* Whh0 = (const float*)d_in[2];
  const float* bih0 = (const float*)d_in[3];
  const float* bhh0 = (const float*)d_in[4];
  const float* Wih1 = (const float*)d_in[5];
  const float* Whh1 = (const float*)d_in[6];
  const float* bih1 = (const float*)d_in[7];
  const float* bhh1 = (const float*)d_in[8];
  const float* Wfc = (const float*)d_in[9];
  const float* bfc = (const float*)d_in[10];

  short* wb = (short*)d_ws;
  short* h1g = wb + H1G_OFF;
  short* h2g = wb + H2G_OFF;
  unsigned* flags = (unsigned*)((char*)d_ws + FLAGS_OFF_BYTES);
  unsigned* hz = (unsigned*)(wb + H1G_OFF);

  cvt_weights<<<(W_TOTAL + 255) / 256, 256, 0, stream>>>(Wih0, Whh0, Wih1, Whh1, wb);
  init_state<<<(2 * BB * HH + 255) / 256, 256, 0, stream>>>(hz, flags);
  gru_sync<<<512, 64, 0, stream>>>(x, wb, bih0, bhh0, bih1, bhh1, Wfc, bfc,
                                   h1g, h2g, flags, (float*)d_out);
}

// Round 10
// 1945.958 us; speedup vs baseline: 3.2575x; 1.0566x over previous
//
#include <hip/hip_runtime.h>

#define TT 512
#define BB 256
#define II 128
#define HH 256

typedef __attribute__((ext_vector_type(8))) short short8;
typedef __attribute__((ext_vector_type(4))) float floatx4;
typedef __attribute__((ext_vector_type(4))) float fvec4;
typedef unsigned long long u64;

// ws layout (shorts): bf16 weights, h1g[2][B][H], h2g[2][B][H], then flags.
#define OFF_WIH0 0
#define OFF_WHH0 (OFF_WIH0 + 3 * HH * II)
#define OFF_WIH1 (OFF_WHH0 + 3 * HH * HH)
#define OFF_WHH1 (OFF_WIH1 + 3 * HH * HH)
#define W_TOTAL (OFF_WHH1 + 3 * HH * HH)
#define H1G_OFF W_TOTAL
#define H2G_OFF (H1G_OFF + 2 * BB * HH)
#define WS_SHORTS (H2G_OFF + 2 * BB * HH)
#define FLAGS_OFF_BYTES (WS_SHORTS * 2)
#define FLAG_STRIDE 32       // uints per bt-group; 16 flags in one 64B line
#define HPARW (BB * HH / 4)  // u64 words per parity buffer = 16384

struct U64x2 { u64 lo, hi; };

__device__ __forceinline__ short f2bf(float f) {
  unsigned u = __builtin_bit_cast(unsigned, f);
  u = u + 0x7fffu + ((u >> 16) & 1u);
  return (short)(u >> 16);
}
__device__ __forceinline__ float fast_sigmoid(float x) {
  return __fdividef(1.0f, 1.0f + __expf(-x));
}
__device__ __forceinline__ float fast_tanh(float x) {
  return 1.0f - __fdividef(2.0f, 1.0f + __expf(2.0f * x));
}
__device__ __forceinline__ short8 cvt8(const float* __restrict__ p) {
  fvec4 lo = *(const fvec4*)p;
  fvec4 hi = *(const fvec4*)(p + 4);
  short8 r;
  r[0] = f2bf(lo[0]); r[1] = f2bf(lo[1]); r[2] = f2bf(lo[2]); r[3] = f2bf(lo[3]);
  r[4] = f2bf(hi[0]); r[5] = f2bf(hi[1]); r[6] = f2bf(hi[2]); r[7] = f2bf(hi[3]);
  return r;
}
__device__ __forceinline__ u64 ld_sc1(const u64* p) {
  return __hip_atomic_load(p, __ATOMIC_RELAXED, __HIP_MEMORY_SCOPE_AGENT);
}
__device__ __forceinline__ unsigned ld_flag(const unsigned* p) {
  return __hip_atomic_load(p, __ATOMIC_RELAXED, __HIP_MEMORY_SCOPE_AGENT);
}
__device__ __forceinline__ void st_flag(unsigned* p, unsigned v) {
  __hip_atomic_store(p, v, __ATOMIC_RELAXED, __HIP_MEMORY_SCOPE_AGENT);
}
__device__ __forceinline__ void st_u32(unsigned* p, unsigned v) {
  __hip_atomic_store(p, v, __ATOMIC_RELAXED, __HIP_MEMORY_SCOPE_AGENT);
}

__global__ __launch_bounds__(256) void cvt_weights(
    const float* __restrict__ w0, const float* __restrict__ w1,
    const float* __restrict__ w2, const float* __restrict__ w3,
    short* __restrict__ out) {
  int i = blockIdx.x * 256 + threadIdx.x;
  if (i >= W_TOTAL) return;
  float v;
  if (i < OFF_WHH0)      v = w0[i - OFF_WIH0];
  else if (i < OFF_WIH1) v = w1[i - OFF_WHH0];
  else if (i < OFF_WHH1) v = w2[i - OFF_WIH1];
  else                   v = w3[i - OFF_WHH1];
  out[i] = f2bf(v);
}

__global__ __launch_bounds__(256) void init_state(unsigned* __restrict__ hz,
                                                  unsigned* __restrict__ flags) {
  int i = blockIdx.x * 256 + threadIdx.x;
  if (i < 2 * BB * HH) hz[i] = 0u;  // h1g+h2g = 4*B*H shorts = 2*B*H uints
  if (i < 32 * FLAG_STRIDE) flags[i] = 0u;
}

// 256 blocks = (bt 0..15) x (ht 0..15), 128 thr = 2 waves.
// Placement: bid&15 = bt -> round-robin puts the whole bt-group on XCD bt%8
// (R8/R9 lesson: exchange stays XCD-local).
// Wave 0 = layer 0, wave 1 = layer 1; each wave owns ALL 3 gates of its 16
// output cols (R9's validated gates-in-lane layout): no gt LDS, no inter-gate
// barriers, A-frags staged straight to VGPRs via ld_sc1 (no LDS at all).
// R3's PROVEN single fused chain: phase p computes h1[p] (w0) and h2[p-1]
// (w1); one poll + one __syncthreads (compiler drains all publishes, R3-
// verified) + one flag store covering both layers. Publishes are 4B dwords
// (R3's width) via 2-lane shfl_xor packing. Lockstep invariant: flag>=p+1
// implies every block staged h1[p-1]/h2[p-2], so parity-2 buffers are safe.
__global__ __launch_bounds__(128) void gru_sync(
    const float* __restrict__ x, const short* __restrict__ wb,
    const float* __restrict__ bih0, const float* __restrict__ bhh0,
    const float* __restrict__ bih1, const float* __restrict__ bhh1,
    const float* __restrict__ Wfc, const float* __restrict__ bfc,
    short* __restrict__ h1g, short* __restrict__ h2g,
    unsigned* __restrict__ flags, float* __restrict__ out) {
  const int tid = threadIdx.x;
  const int lane = tid & 63;
  const int w = tid >> 6;       // 0 = layer0, 1 = layer1
  const int quad = lane >> 4;
  const int col = lane & 15;
  const int bt = blockIdx.x & 15;   // XCD = bt%8
  const int ht = blockIdx.x >> 4;
  const int layer = w;
  const int j = ht * 16 + col;

  unsigned* fl = flags + bt * FLAG_STRIDE;  // 16 slots, one 64B line

  // ---- weights -> VGPRs: all 3 gates of this wave's layer ----
  const short* wih = wb + (layer ? OFF_WIH1 : OFF_WIH0);
  const short* whh = wb + (layer ? OFF_WHH1 : OFF_WHH0);
  const int KI = layer ? HH : II;
  short8 wI0[8], wI1[8], wI2[8], wH0[8], wH1[8], wH2[8];
#pragma unroll
  for (int f = 0; f < 8; ++f) {
    if (f * 32 < KI) {
      wI0[f] = *(const short8*)(wih + (0 * HH + j) * KI + f * 32 + quad * 8);
      wI1[f] = *(const short8*)(wih + (1 * HH + j) * KI + f * 32 + quad * 8);
      wI2[f] = *(const short8*)(wih + (2 * HH + j) * KI + f * 32 + quad * 8);
    } else {
      wI0[f] = short8{0,0,0,0,0,0,0,0};
      wI1[f] = short8{0,0,0,0,0,0,0,0};
      wI2[f] = short8{0,0,0,0,0,0,0,0};
    }
    wH0[f] = *(const short8*)(whh + (0 * HH + j) * HH + f * 32 + quad * 8);
    wH1[f] = *(const short8*)(whh + (1 * HH + j) * HH + f * 32 + quad * 8);
    wH2[f] = *(const short8*)(whh + (2 * HH + j) * HH + f * 32 + quad * 8);
  }
  const float* bihL = layer ? bih1 : bih0;
  const float* bhhL = layer ? bhh1 : bhh0;
  const float bI0 = bihL[j] + bhhL[j];
  const float bI1 = bihL[HH + j] + bhhL[HH + j];
  const float bI2 = bihL[2 * HH + j];
  const float bH2 = bhhL[2 * HH + j];

  // recurrent state in regs: h[bt*16+quad*4+i][j], i=0..3 (this wave's layer)
  float hprev0 = 0.f, hprev1 = 0.f, hprev2 = 0.f, hprev3 = 0.f;

  const u64* h1w = (const u64*)h1g;
  const u64* h2w = (const u64*)h2g;
  const int rowW = (bt * 16 + col) * 64;  // u64 words per h row (R9-proven)

  for (int p = 0; p <= TT; ++p) {
    // x prefetch (wave 0 only; plain cached loads, before the poll)
    short8 ax[4];
    if (w == 0 && p < TT) {
      const float* xr = x + ((size_t)p * BB + bt * 16 + col) * II + quad * 8;
#pragma unroll
      for (int f = 0; f < 4; ++f) ax[f] = cvt8(xr + f * 32);
    }

    // ---- poll: both waves watch the 16-flag line (64B) until >= p ----
    if (p > 0) {
      const unsigned tgt = (unsigned)p;
      int guard = 0;
      for (;;) {
        unsigned v = (lane < 16) ? ld_flag(fl + lane) : tgt;
        if (__all(v >= tgt) || ++guard > (1 << 20)) break;
        __builtin_amdgcn_s_sleep(1);  // throttle L2 line contention
      }
    }

    // ---- stage A-frags straight to VGPRs (R9-proven addressing) ----
    short8 a1[8], a2[8];
    {
      const u64* s1 = h1w + ((p + 1) & 1) * HPARW + rowW;  // h1[p-1]
#pragma unroll
      for (int f = 0; f < 8; ++f) {
        u64 lo = ld_sc1(s1 + f * 8 + quad * 2);
        u64 hi = ld_sc1(s1 + f * 8 + quad * 2 + 1);
        a1[f] = __builtin_bit_cast(short8, U64x2{lo, hi});
      }
      if (w == 1) {
        const u64* s2 = h2w + (p & 1) * HPARW + rowW;      // h2[p-2]
#pragma unroll
        for (int f = 0; f < 8; ++f) {
          u64 lo = ld_sc1(s2 + f * 8 + quad * 2);
          u64 hi = ld_sc1(s2 + f * 8 + quad * 2 + 1);
          a2[f] = __builtin_bit_cast(short8, U64x2{lo, hi});
        }
      }
    }

    // ---- MFMA: all 3 gates of this wave's layer ----
    floatx4 aR = floatx4{bI0, bI0, bI0, bI0};
    floatx4 aZ = floatx4{bI1, bI1, bI1, bI1};
    floatx4 aN = floatx4{bI2, bI2, bI2, bI2};
    floatx4 hN = floatx4{bH2, bH2, bH2, bH2};
    if (w == 0) {
      if (p < TT) {
#pragma unroll
        for (int f = 0; f < 4; ++f) {  // IH: x[p] (K=128)
          aR = __builtin_amdgcn_mfma_f32_16x16x32_bf16(ax[f], wI0[f], aR, 0, 0, 0);
          aZ = __builtin_amdgcn_mfma_f32_16x16x32_bf16(ax[f], wI1[f], aZ, 0, 0, 0);
          aN = __builtin_amdgcn_mfma_f32_16x16x32_bf16(ax[f], wI2[f], aN, 0, 0, 0);
        }
#pragma unroll
        for (int f = 0; f < 8; ++f) {  // HH: h1[p-1]
          aR = __builtin_amdgcn_mfma_f32_16x16x32_bf16(a1[f], wH0[f], aR, 0, 0, 0);
          aZ = __builtin_amdgcn_mfma_f32_16x16x32_bf16(a1[f], wH1[f], aZ, 0, 0, 0);
          hN = __builtin_amdgcn_mfma_f32_16x16x32_bf16(a1[f], wH2[f], hN, 0, 0, 0);
        }
      }
    } else {
      if (p > 0) {
#pragma unroll
        for (int f = 0; f < 8; ++f) {  // IH: h1[p-1]
          aR = __builtin_amdgcn_mfma_f32_16x16x32_bf16(a1[f], wI0[f], aR, 0, 0, 0);
          aZ = __builtin_amdgcn_mfma_f32_16x16x32_bf16(a1[f], wI1[f], aZ, 0, 0, 0);
          aN = __builtin_amdgcn_mfma_f32_16x16x32_bf16(a1[f], wI2[f], aN, 0, 0, 0);
        }
#pragma unroll
        for (int f = 0; f < 8; ++f) {  // HH: h2[p-2]
          aR = __builtin_amdgcn_mfma_f32_16x16x32_bf16(a2[f], wH0[f], aR, 0, 0, 0);
          aZ = __builtin_amdgcn_mfma_f32_16x16x32_bf16(a2[f], wH1[f], aZ, 0, 0, 0);
          hN = __builtin_amdgcn_mfma_f32_16x16x32_bf16(a2[f], wH2[f], hN, 0, 0, 0);
        }
      }
    }

    // ---- elementwise in-lane + 4B packed publish (even cols store) ----
    const bool doPub = (w == 0) ? (p < TT) : (p > 0);
    if (doPub) {
      float r0 = fast_sigmoid(aR[0]), z0 = fast_sigmoid(aZ[0]);
      float n0 = fast_tanh(aN[0] + r0 * hN[0]);
      hprev0 = n0 + z0 * (hprev0 - n0);
      float r1 = fast_sigmoid(aR[1]), z1 = fast_sigmoid(aZ[1]);
      float n1 = fast_tanh(aN[1] + r1 * hN[1]);
      hprev1 = n1 + z1 * (hprev1 - n1);
      float r2 = fast_sigmoid(aR[2]), z2 = fast_sigmoid(aZ[2]);
      float n2 = fast_tanh(aN[2] + r2 * hN[2]);
      hprev2 = n2 + z2 * (hprev2 - n2);
      float r3 = fast_sigmoid(aR[3]), z3 = fast_sigmoid(aZ[3]);
      float n3 = fast_tanh(aN[3] + r3 * hN[3]);
      hprev3 = n3 + z3 * (hprev3 - n3);

      unsigned m0 = (unsigned)(unsigned short)f2bf(hprev0);
      unsigned m1 = (unsigned)(unsigned short)f2bf(hprev1);
      unsigned m2 = (unsigned)(unsigned short)f2bf(hprev2);
      unsigned m3 = (unsigned)(unsigned short)f2bf(hprev3);
      unsigned o0 = (unsigned)__shfl_xor((int)m0, 1);
      unsigned o1 = (unsigned)__shfl_xor((int)m1, 1);
      unsigned o2 = (unsigned)__shfl_xor((int)m2, 1);
      unsigned o3 = (unsigned)__shfl_xor((int)m3, 1);
      if (!(col & 1)) {
        short* hout = (w == 0) ? (h1g + (p & 1) * BB * HH)
                               : (h2g + ((p + 1) & 1) * BB * HH);
        unsigned* db = (unsigned*)hout;
        const int base = ((bt * 16 + quad * 4) * HH + j) >> 1;  // dword index
        st_u32(db + base + 0 * (HH / 2), m0 | (o0 << 16));
        st_u32(db + base + 1 * (HH / 2), m1 | (o1 << 16));
        st_u32(db + base + 2 * (HH / 2), m2 | (o2 << 16));
        st_u32(db + base + 3 * (HH / 2), m3 | (o3 << 16));
      }
    }
    __syncthreads();  // compiler-inserted vmcnt(0) drains both waves' stores
    if (tid == 0) st_flag(fl + ht, (unsigned)(p + 1));
  }

  // ---- FC epilogue: wave 0 computes out = h2[TT-1] @ Wfc^T + bfc ----
  if (w == 0) {
    const unsigned tgt = (unsigned)(TT + 1);
    int guard = 0;
    for (;;) {
      unsigned v = (lane < 16) ? ld_flag(fl + lane) : tgt;
      if (__all(v >= tgt) || ++guard > (1 << 20)) break;
      __builtin_amdgcn_s_sleep(1);
    }
    const u64* s2 = h2w + ((TT - 1) & 1) * HPARW + rowW;  // parity 1
    float bbv = bfc[j];
    floatx4 acc = floatx4{bbv, bbv, bbv, bbv};
#pragma unroll
    for (int f = 0; f < 8; ++f) {
      u64 lo = ld_sc1(s2 + f * 8 + quad * 2);
      u64 hi = ld_sc1(s2 + f * 8 + quad * 2 + 1);
      short8 a = __builtin_bit_cast(short8, U64x2{lo, hi});
      short8 bfrag = cvt8(Wfc + j * HH + f * 32 + quad * 8);
      acc = __builtin_amdgcn_mfma_f32_16x16x32_bf16(a, bfrag, acc, 0, 0, 0);
    }
#pragma unroll
    for (int i = 0; i < 4; ++i)
      out[(size_t)(bt * 16 + quad * 4 + i) * HH + j] = acc[i];
  }
}

extern "C" void kernel_launch(void* const* d_in, const int* in_sizes, int n_in,
                              void* d_out, int out_size, void* d_ws,
                              size_t ws_size, hipStream_t stream) {
  const float* x = (const float*)d_in[0];
  const float* Wih0 = (const float*)d_in[1];
  const float* Whh0 = (const float*)d_in[2];
  const float* bih0 = (const float*)d_in[3];
  const float* bhh0 = (const float*)d_in[4];
  const float* Wih1 = (const float*)d_in[5];
  const float* Whh1 = (const float*)d_in[6];
  const float* bih1 = (const float*)d_in[7];
  const float* bhh1 = (const float*)d_in[8];
  const float* Wfc = (const float*)d_in[9];
  const float* bfc = (const float*)d_in[10];

  short* wb = (short*)d_ws;
  short* h1g = wb + H1G_OFF;
  short* h2g = wb + H2G_OFF;
  unsigned* flags = (unsigned*)((char*)d_ws + FLAGS_OFF_BYTES);
  unsigned* hz = (unsigned*)(wb + H1G_OFF);

  cvt_weights<<<(W_TOTAL + 255) / 256, 256, 0, stream>>>(Wih0, Whh0, Wih1, Whh1, wb);
  init_state<<<(2 * BB * HH + 255) / 256, 256, 0, stream>>>(hz, flags);
  gru_sync<<<256, 128, 0, stream>>>(x, wb, bih0, bhh0, bih1, bhh1, Wfc, bfc,
                                    h1g, h2g, flags, (float*)d_out);
}